// Round 6
// baseline (52.528 us; speedup 1.0000x reference)
//
#include <hip/hip_runtime.h>

// DIAGNOSTIC ROUND: identical to R5 except cd_partial runs its chunk loop
// TWICE (idempotent min; barrier between passes blocks CSE). Purpose: pin
// K1's true duration (dur_us - 33.9) and surface its counters in top-5.

#define BATCH 8
#define NPTS 4096
#define THREADS 256
#define TQ 8
#define QB (TQ*THREADS)          // 2048
#define QBLKS (NPTS/QB)          // 2
#define CHUNKS 32
#define CHUNK (NPTS/CHUNKS)      // 128
#define NSLOT (2*BATCH*NPTS)     // 65536
#define RBLKS (NSLOT/256)        // 256

__global__ __launch_bounds__(THREADS, 4) void cd_partial(
        const float* __restrict__ pred,
        const float* __restrict__ targ,
        float* __restrict__ P) {
    const int qblk  = blockIdx.x;
    const int chunk = blockIdx.y;
    const int dirb  = blockIdx.z;
    const int dir   = dirb >> 3;
    const int b     = dirb & 7;
    const int tid   = threadIdx.x;
    const float* Q  = dir ? targ : pred;
    const float* Db = dir ? pred : targ;

    __shared__ float4 sdb[CHUNK];
    if (tid < CHUNK) {
        const float* p = Db + ((size_t)b * NPTS + (size_t)chunk * CHUNK + tid) * 3;
        float x = p[0], y = p[1], z = p[2];
        sdb[tid] = make_float4(x, y, z, fmaf(x, x, fmaf(y, y, z * z)));
    }
    __syncthreads();

    float qx[TQ], qy[TQ], qz[TQ], m[TQ];
    const int q0 = qblk * QB + tid;
    #pragma unroll
    for (int k = 0; k < TQ; ++k) {
        const float* p = Q + ((size_t)b * NPTS + q0 + k * THREADS) * 3;
        qx[k] = -2.f * p[0]; qy[k] = -2.f * p[1]; qz[k] = -2.f * p[2];
        m[k]  = __uint_as_float(0x7F800000u);
    }

    for (int pass = 0; pass < 2; ++pass) {   // DIAGNOSTIC: 2x identical work
        #pragma unroll 4
        for (int j = 0; j < CHUNK; j += 2) {
            float4 b0 = sdb[j];
            float4 b1 = sdb[j + 1];
            #pragma unroll
            for (int k = 0; k < TQ; ++k) {
                float t0 = fmaf(qx[k], b0.x, fmaf(qy[k], b0.y, fmaf(qz[k], b0.z, b0.w)));
                float t1 = fmaf(qx[k], b1.x, fmaf(qy[k], b1.y, fmaf(qz[k], b1.z, b1.w)));
                m[k] = fminf(m[k], fminf(t0, t1));
            }
        }
        __syncthreads();   // blocks CSE of the second pass
    }

    float* o = P + (size_t)chunk * NSLOT + (size_t)dirb * NPTS + q0;
    #pragma unroll
    for (int k = 0; k < TQ; ++k) o[k * THREADS] = m[k];
}

__global__ __launch_bounds__(256) void cd_reduce(
        const float* __restrict__ pred,
        const float* __restrict__ targ,
        const float* __restrict__ P,
        float* __restrict__ Bsum) {
    const int tid  = threadIdx.x;
    const int slot = blockIdx.x * 256 + tid;
    const int dirb = slot >> 12;
    const int q    = slot & (NPTS - 1);
    const int b    = dirb & 7;

    const float* p = ((dirb >> 3) ? targ : pred) + ((size_t)b * NPTS + q) * 3;
    float x = p[0], y = p[1], z = p[2];
    float nq = fmaf(x, x, fmaf(y, y, z * z));

    float m = __uint_as_float(0x7F800000u);
    #pragma unroll
    for (int c = 0; c < CHUNKS; c += 2)
        m = fminf(m, fminf(P[(size_t)c * NSLOT + slot],
                           P[(size_t)(c + 1) * NSLOT + slot]));

    float s = sqrtf(fmaxf(nq + m, 0.f));
    #pragma unroll
    for (int off = 32; off > 0; off >>= 1) s += __shfl_down(s, off);

    __shared__ float wsum[4];
    if ((tid & 63) == 0) wsum[tid >> 6] = s;
    __syncthreads();
    if (tid == 0)
        Bsum[blockIdx.x] = (wsum[0] + wsum[1]) + (wsum[2] + wsum[3]);
}

__global__ __launch_bounds__(64) void cd_final(
        const float* __restrict__ Bsum, float* __restrict__ out) {
    const int tid = threadIdx.x;
    float s = 0.f;
    #pragma unroll
    for (int i = 0; i < RBLKS; i += 64) s += Bsum[i + tid];
    #pragma unroll
    for (int off = 32; off > 0; off >>= 1) s += __shfl_down(s, off);
    if (tid == 0) out[0] = s * (1.0f / (float)(BATCH * NPTS));
}

extern "C" void kernel_launch(void* const* d_in, const int* in_sizes, int n_in,
                              void* d_out, int out_size, void* d_ws, size_t ws_size,
                              hipStream_t stream) {
    const float* pred = (const float*)d_in[0];
    const float* targ = (const float*)d_in[1];
    float* P    = (float*)d_ws;                                       // 8 MB
    float* Bsum = (float*)((char*)d_ws + (size_t)CHUNKS * NSLOT * 4); // 1 KB
    float* out  = (float*)d_out;

    cd_partial<<<dim3(QBLKS, CHUNKS, 2 * BATCH), THREADS, 0, stream>>>(pred, targ, P);
    cd_reduce<<<RBLKS, 256, 0, stream>>>(pred, targ, P, Bsum);
    cd_final<<<1, 64, 0, stream>>>(Bsum, out);
}

// Round 7
// 46.795 us; speedup vs baseline: 1.1225x; 1.1225x over previous
//
#include <hip/hip_runtime.h>

// Chamfer distance, B=8, N=M=4096, fp32 — 4 dispatches, zero atomics.
// K0 cd_prep:    (x,y,z,|p|^2) float4 tables for both clouds (coalesced loads).
// K1 cd_partial: per (qblk, chunk, dirb) block: 2048 queries x 128 db points,
//                SoA LDS staging, v_pk_fma_f32 packed inner loop (2 cols/step),
//                partial row-mins of (|b|^2 - 2 q.b) -> P.
// K2 cd_reduce:  per-slot min over 32 chunks, +|q|^2 (from table), sqrt,
//                block tree sum -> Bsum[256].
// K3 cd_final:   1 wave sums Bsum -> loss.

typedef float f32x2 __attribute__((ext_vector_type(2)));

#define BATCH 8
#define NPTS 4096
#define THREADS 256
#define TQ 8
#define QB (TQ*THREADS)          // 2048
#define QBLKS (NPTS/QB)          // 2
#define CHUNKS 32
#define CHUNK (NPTS/CHUNKS)      // 128
#define NSLOT (2*BATCH*NPTS)     // 65536
#define NCLOUD (BATCH*NPTS)      // 32768
#define RBLKS (NSLOT/256)        // 256

__global__ __launch_bounds__(256) void cd_prep(
        const float* __restrict__ pred,
        const float* __restrict__ targ,
        float4* __restrict__ pts4) {
    int i = blockIdx.x * 256 + threadIdx.x;     // 0..2*NCLOUD-1
    const float* src = (i < NCLOUD) ? pred : targ;
    int idx = i & (NCLOUD - 1);
    const float* p = src + (size_t)idx * 3;
    float x = p[0], y = p[1], z = p[2];
    pts4[i] = make_float4(x, y, z, fmaf(x, x, fmaf(y, y, z * z)));
}

__global__ __launch_bounds__(THREADS, 4) void cd_partial(
        const float4* __restrict__ pts4,
        float* __restrict__ P) {
    const int qblk  = blockIdx.x;      // 0..QBLKS-1
    const int chunk = blockIdx.y;      // 0..CHUNKS-1
    const int dirb  = blockIdx.z;      // dir*BATCH + b
    const int dir   = dirb >> 3;
    const int b     = dirb & 7;
    const int tid   = threadIdx.x;

    const float4* Q  = pts4 + (dir ? NCLOUD : 0) + (size_t)b * NPTS;
    const float4* Db = pts4 + (dir ? 0 : NCLOUD) + (size_t)b * NPTS
                            + (size_t)chunk * CHUNK;

    // SoA LDS staging: 8B-aligned so f32x2 reads are natural ds_read_b64
    __shared__ __align__(16) float s_x[CHUNK], s_y[CHUNK], s_z[CHUNK], s_w[CHUNK];
    if (tid < CHUNK) {
        float4 d = Db[tid];
        s_x[tid] = d.x; s_y[tid] = d.y; s_z[tid] = d.z; s_w[tid] = d.w;
    }
    __syncthreads();

    // queries: duplicated pairs for packed math
    f32x2 qx2[TQ], qy2[TQ], qz2[TQ];
    float m[TQ];
    const int q0 = qblk * QB + tid;
    #pragma unroll
    for (int k = 0; k < TQ; ++k) {
        float4 qp = Q[q0 + k * THREADS];        // coalesced 16B/lane
        float ax = -2.f * qp.x, ay = -2.f * qp.y, az = -2.f * qp.z;
        qx2[k] = (f32x2){ax, ax};
        qy2[k] = (f32x2){ay, ay};
        qz2[k] = (f32x2){az, az};
        m[k]   = __uint_as_float(0x7F800000u);
    }

    #pragma unroll 4
    for (int j = 0; j < CHUNK; j += 2) {
        f32x2 bx = *(const f32x2*)&s_x[j];      // ds_read_b64, broadcast
        f32x2 by = *(const f32x2*)&s_y[j];
        f32x2 bz = *(const f32x2*)&s_z[j];
        f32x2 bw = *(const f32x2*)&s_w[j];
        #pragma unroll
        for (int k = 0; k < TQ; ++k) {
            f32x2 t;
            asm("v_pk_fma_f32 %0, %1, %2, %3"
                : "=v"(t) : "v"(qz2[k]), "v"(bz), "v"(bw));
            asm("v_pk_fma_f32 %0, %1, %2, %0"
                : "+v"(t) : "v"(qy2[k]), "v"(by));
            asm("v_pk_fma_f32 %0, %1, %2, %0"
                : "+v"(t) : "v"(qx2[k]), "v"(bx));
            m[k] = fminf(m[k], fminf(t.x, t.y));   // -> v_min3_f32
        }
    }

    float* o = P + (size_t)chunk * NSLOT + (size_t)dirb * NPTS + q0;
    #pragma unroll
    for (int k = 0; k < TQ; ++k) o[k * THREADS] = m[k];
}

__global__ __launch_bounds__(256) void cd_reduce(
        const float4* __restrict__ pts4,
        const float* __restrict__ P,
        float* __restrict__ Bsum) {
    const int tid  = threadIdx.x;
    const int slot = blockIdx.x * 256 + tid;   // 0..NSLOT-1
    const int dirb = slot >> 12;
    const int q    = slot & (NPTS - 1);
    const int dir  = dirb >> 3;
    const int b    = dirb & 7;

    float nq = pts4[(dir ? NCLOUD : 0) + (size_t)b * NPTS + q].w;

    float m = __uint_as_float(0x7F800000u);
    #pragma unroll
    for (int c = 0; c < CHUNKS; c += 2)
        m = fminf(m, fminf(P[(size_t)c * NSLOT + slot],
                           P[(size_t)(c + 1) * NSLOT + slot]));

    float s = sqrtf(fmaxf(nq + m, 0.f));
    #pragma unroll
    for (int off = 32; off > 0; off >>= 1) s += __shfl_down(s, off);

    __shared__ float wsum[4];
    if ((tid & 63) == 0) wsum[tid >> 6] = s;
    __syncthreads();
    if (tid == 0)
        Bsum[blockIdx.x] = (wsum[0] + wsum[1]) + (wsum[2] + wsum[3]);
}

__global__ __launch_bounds__(64) void cd_final(
        const float* __restrict__ Bsum, float* __restrict__ out) {
    const int tid = threadIdx.x;
    float s = 0.f;
    #pragma unroll
    for (int i = 0; i < RBLKS; i += 64) s += Bsum[i + tid];
    #pragma unroll
    for (int off = 32; off > 0; off >>= 1) s += __shfl_down(s, off);
    if (tid == 0) out[0] = s * (1.0f / (float)(BATCH * NPTS));
}

extern "C" void kernel_launch(void* const* d_in, const int* in_sizes, int n_in,
                              void* d_out, int out_size, void* d_ws, size_t ws_size,
                              hipStream_t stream) {
    const float* pred = (const float*)d_in[0];
    const float* targ = (const float*)d_in[1];
    float* P     = (float*)d_ws;                                        // 8 MB
    float* Bsum  = (float*)((char*)d_ws + (size_t)CHUNKS * NSLOT * 4);  // 1 KB
    float4* pts4 = (float4*)((char*)d_ws + (size_t)CHUNKS * NSLOT * 4 + 4096); // 1 MB
    float* out   = (float*)d_out;

    cd_prep<<<2 * NCLOUD / 256, 256, 0, stream>>>(pred, targ, pts4);
    cd_partial<<<dim3(QBLKS, CHUNKS, 2 * BATCH), THREADS, 0, stream>>>(pts4, P);
    cd_reduce<<<RBLKS, 256, 0, stream>>>(pts4, P, Bsum);
    cd_final<<<1, 64, 0, stream>>>(Bsum, out);
}

// Round 8
// 32.181 us; speedup vs baseline: 1.6323x; 1.4541x over previous
//
#include <hip/hip_runtime.h>

// Chamfer distance, B=8, N=M=4096, fp32 in/out — MFMA (bf16) path.
//   d^2 = |q~|^2 + (hi+lo) - 2 q~.b~   via  mfma_f32_32x32x16_bf16
//   A (32x16) = db tile rows: k = {x~, y~, z~, hi(|b~|^2), lo, 0...}
//   B (16x32) = query cols:   k = {-2x~, -2y~, -2z~, 1, 1, 0...}
//   C layout: col = lane&31 (query), rows = db -> min over db is IN-LANE.
// K0 cd_prep:  bf16-round coords, build dbpack/qpack (16B/pt) + |q~|^2 f32.
// K1 cd_mfma:  per (dirb, 4-coltile) block: stage 64KB db in LDS, each wave
//              does 128 MFMA tiles + in-lane min-fold, epilogue sqrt+sum,
//              one float per wave -> Bsum[2048]. Zero atomics.
// K2 cd_final: 1 block sums Bsum deterministically -> loss.

typedef __bf16 bf16x8  __attribute__((ext_vector_type(8)));
typedef float  f32x16  __attribute__((ext_vector_type(16)));

#define BATCH 8
#define NPTS 4096
#define NCLOUD (BATCH*NPTS)      // 32768 points per cloud
#define DIRB 16                  // 2 dirs x 8 batches
#define COLTILES (NPTS/32)       // 128 query column-tiles per dirb
#define K1_BLOCKS (DIRB*COLTILES/4)  // 512 (4 waves/block, 1 coltile/wave)
#define NWAVES (DIRB*COLTILES)   // 2048

__device__ __forceinline__ unsigned short f2bf(float f) {   // RTNE
    unsigned u = __float_as_uint(f);
    unsigned r = u + 0x7FFFu + ((u >> 16) & 1u);
    return (unsigned short)(r >> 16);
}
__device__ __forceinline__ float bf2f(unsigned short h) {
    return __uint_as_float(((unsigned)h) << 16);
}

__global__ __launch_bounds__(256) void cd_prep(
        const float* __restrict__ pred,
        const float* __restrict__ targ,
        uint4* __restrict__ dbpack,
        uint4* __restrict__ qpack,
        float* __restrict__ nqtab) {
    int i = blockIdx.x * 256 + threadIdx.x;     // 0..2*NCLOUD-1
    const float* src = (i < NCLOUD) ? pred : targ;
    const float* p = src + (size_t)(i & (NCLOUD - 1)) * 3;
    unsigned short bx = f2bf(p[0]), by = f2bf(p[1]), bz = f2bf(p[2]);
    float xr = bf2f(bx), yr = bf2f(by), zr = bf2f(bz);
    float w = fmaf(xr, xr, fmaf(yr, yr, zr * zr));
    unsigned short hi = f2bf(w);
    unsigned short lo = f2bf(w - bf2f(hi));
    unsigned short mx = f2bf(-2.f * xr), my = f2bf(-2.f * yr), mz = f2bf(-2.f * zr);
    const unsigned short one = 0x3F80;  // 1.0 bf16

    dbpack[i] = make_uint4((unsigned)bx | ((unsigned)by << 16),
                           (unsigned)bz | ((unsigned)hi << 16),
                           (unsigned)lo, 0u);
    qpack[i]  = make_uint4((unsigned)mx | ((unsigned)my << 16),
                           (unsigned)mz | ((unsigned)one << 16),
                           (unsigned)one, 0u);
    nqtab[i]  = w;
}

__global__ __launch_bounds__(256, 2) void cd_mfma(
        const uint4* __restrict__ dbpack,
        const uint4* __restrict__ qpack,
        const float* __restrict__ nqtab,
        float* __restrict__ Bsum) {
    __shared__ uint4 sdb[NPTS + 1];      // 64 KB db packets + 16B zero entry
    const int bx   = blockIdx.x;         // 0..511
    const int tid  = threadIdx.x;
    const int dirb = bx >> 5;            // 0..15
    const int ctg  = bx & 31;            // coltile group
    const int wave = tid >> 6;
    const int lane = tid & 63;
    const int dir  = dirb >> 3;
    const int b    = dirb & 7;
    const int dbc  = 1 - dir;            // db cloud (0=pred,1=targ)
    const int qc   = dir;                // query cloud

    // stage this (dbc,b)'s 4096 packets into LDS
    const uint4* src = dbpack + ((size_t)dbc * NCLOUD + (size_t)b * NPTS);
    for (int i = tid; i < NPTS; i += 256) sdb[i] = src[i];
    if (tid == 0) sdb[NPTS] = make_uint4(0u, 0u, 0u, 0u);
    __syncthreads();

    // B operand: 32 queries; lanes 32..63 (k=8..15) must be zero
    const int coltile = ctg * 4 + wave;
    const int q = coltile * 32 + (lane & 31);
    uint4 qv = qpack[(size_t)qc * NCLOUD + (size_t)b * NPTS + q];
    uint4 z4 = make_uint4(0u, 0u, 0u, 0u);
    uint4 bqv = (lane < 32) ? qv : z4;
    bf16x8 Bf = __builtin_bit_cast(bf16x8, bqv);

    // A addressing: lanes 0..31 walk db tiles; lanes 32..63 pin the zero entry
    const char* sb = (const char*)sdb;
    int off  = (lane < 32) ? ((lane & 31) * 16) : (NPTS * 16);
    int step = (lane < 32) ? 512 : 0;

    const float inf = __uint_as_float(0x7F800000u);
    float m0 = inf, m1 = inf;
    auto fold = [&](const f32x16& a) {
        m0 = fminf(m0, fminf(a[0],  a[1]));
        m0 = fminf(m0, fminf(a[2],  a[3]));
        m0 = fminf(m0, fminf(a[4],  a[5]));
        m0 = fminf(m0, fminf(a[6],  a[7]));
        m1 = fminf(m1, fminf(a[8],  a[9]));
        m1 = fminf(m1, fminf(a[10], a[11]));
        m1 = fminf(m1, fminf(a[12], a[13]));
        m1 = fminf(m1, fminf(a[14], a[15]));
    };

    // 128 db tiles, 2 MFMAs in flight (fold lags by one slot)
    uint4 a0 = *(const uint4*)(sb + off); off += step;
    f32x16 accA = __builtin_amdgcn_mfma_f32_32x32x16_bf16(
            __builtin_bit_cast(bf16x8, a0), Bf, (f32x16){}, 0, 0, 0);
    uint4 a1 = *(const uint4*)(sb + off); off += step;
    f32x16 accB = __builtin_amdgcn_mfma_f32_32x32x16_bf16(
            __builtin_bit_cast(bf16x8, a1), Bf, (f32x16){}, 0, 0, 0);
    #pragma unroll 4
    for (int j = 2; j < COLTILES; j += 2) {
        uint4 an = *(const uint4*)(sb + off); off += step;
        fold(accA);
        accA = __builtin_amdgcn_mfma_f32_32x32x16_bf16(
                __builtin_bit_cast(bf16x8, an), Bf, (f32x16){}, 0, 0, 0);
        uint4 am = *(const uint4*)(sb + off); off += step;
        fold(accB);
        accB = __builtin_amdgcn_mfma_f32_32x32x16_bf16(
                __builtin_bit_cast(bf16x8, am), Bf, (f32x16){}, 0, 0, 0);
    }
    fold(accA);
    fold(accB);

    // epilogue: combine row-halves, add |q~|^2, sqrt, sum 32 queries
    float m = fminf(m0, m1);
    m = fminf(m, __shfl_xor(m, 32, 64));
    float nq = nqtab[(size_t)qc * NCLOUD + (size_t)b * NPTS + q];
    float d = sqrtf(fmaxf(m + nq, 0.f));
    d += __shfl_xor(d, 16, 64);
    d += __shfl_xor(d,  8, 64);
    d += __shfl_xor(d,  4, 64);
    d += __shfl_xor(d,  2, 64);
    d += __shfl_xor(d,  1, 64);
    if (lane == 0) Bsum[bx * 4 + wave] = d;
}

__global__ __launch_bounds__(256) void cd_final(
        const float* __restrict__ Bsum, float* __restrict__ out) {
    const int tid = threadIdx.x;
    float s = 0.f;
    #pragma unroll
    for (int i = 0; i < NWAVES; i += 256) s += Bsum[tid + i];
    __shared__ float red[256];
    red[tid] = s;
    __syncthreads();
    for (int off = 128; off > 0; off >>= 1) {
        if (tid < off) red[tid] += red[tid + off];
        __syncthreads();
    }
    if (tid == 0) out[0] = red[0] * (1.0f / (float)(BATCH * NPTS));
}

extern "C" void kernel_launch(void* const* d_in, const int* in_sizes, int n_in,
                              void* d_out, int out_size, void* d_ws, size_t ws_size,
                              hipStream_t stream) {
    const float* pred = (const float*)d_in[0];
    const float* targ = (const float*)d_in[1];
    char* ws = (char*)d_ws;
    uint4* dbpack = (uint4*)(ws);                         // 1 MB
    uint4* qpack  = (uint4*)(ws + (size_t)2 * NCLOUD * 16);          // 1 MB
    float* nqtab  = (float*)(ws + (size_t)4 * NCLOUD * 16);          // 256 KB
    float* Bsum   = (float*)(ws + (size_t)4 * NCLOUD * 16 + (size_t)2 * NCLOUD * 4); // 8 KB
    float* out    = (float*)d_out;

    cd_prep<<<2 * NCLOUD / 256, 256, 0, stream>>>(pred, targ, dbpack, qpack, nqtab);
    cd_mfma<<<K1_BLOCKS, 256, 0, stream>>>(dbpack, qpack, nqtab, Bsum);
    cd_final<<<1, 256, 0, stream>>>(Bsum, out);
}